// Round 3
// baseline (494.110 us; speedup 1.0000x reference)
//
#include <hip/hip_runtime.h>
#include <math.h>

typedef short v8s __attribute__((ext_vector_type(8)));
typedef float v4f __attribute__((ext_vector_type(4)));

__device__ __forceinline__ short f2bf(float f) {
    union { float f; unsigned u; } x; x.f = f;
    unsigned r = x.u + 0x7FFFu + ((x.u >> 16) & 1u);
    return (short)(r >> 16);
}

// ---------------------------------------------------------------------------
// Build tables in workspace:
//  MnT [64 cols][1024 k] bf16 : dense nope projection matrix (transposed)
//    k = g*128+dp ; part=dp>>6, dpp=dp&63, B=(dpp&1)*16+(dpp>>2), c=g+8*((dpp>>1)&1)
//    MnT[col][k] = sum_{o=1..15} widx[B][c][o] * wn[col][part*480+B*15+o-1]
//  W2 [2][32][64][4] f32 : vt rearranged so weights_kernel lane loads coalesce
//    W2[s][i][l][cc] = vt[h][d][rr], h=(l>>2)+16s, rr=l&3, d=i*4+cc
// ---------------------------------------------------------------------------
__global__ __launch_bounds__(256)
void build_tables(const float* __restrict__ widx,  // [32][16][16]
                  const float* __restrict__ wn,    // [64][960]
                  const float* __restrict__ vt,    // [32][128][4]
                  short* __restrict__ MnT,
                  float* __restrict__ W2)
{
    const int idx = blockIdx.x * 256 + threadIdx.x;   // 81920 total
    if (idx < 65536) {
        const int col = idx >> 10, kk = idx & 1023;
        const int g = kk >> 7, dp = kk & 127;
        const int part = dp >> 6, dpp = dp & 63;
        const int B = (dpp & 1) * 16 + (dpp >> 2);
        const int c = g + 8 * ((dpp >> 1) & 1);
        const float* wrow = wn + col * 960 + part * 480 + B * 15;
        const float* wi   = widx + B * 256 + c * 16;
        float s = 0.f;
#pragma unroll
        for (int o = 1; o < 16; ++o) s += wi[o] * wrow[o - 1];
        MnT[idx] = f2bf(s);
    } else {
        const int t = idx - 65536;                    // [0, 16384)
        const int cc = t & 3, l = (t >> 2) & 63, i = (t >> 8) & 31, s = t >> 13;
        const int h = (l >> 2) + 16 * s, rr = l & 3, d = i * 4 + cc;
        W2[t] = vt[h * 512 + d * 4 + rr];
    }
}

// ---------------------------------------------------------------------------
// Nope GEMM: out[:, 64:128] = A_nope[40960][1024] x Mn[1024][64]
// Blocks 0..1023: Q (8 tokens, 32 rows = 8 tok x 4 jj), A[r][g*128+dp]=q_orig[n][4g+jj][dp]
// Blocks 1024..1279: K (32 tokens, 32 rows), A[r][k]=k_orig[n][k] (contiguous)
// LDS stage per 256-k chunk, coalesced float4 loads + bf16 cvt; padded rows.
// ---------------------------------------------------------------------------
constexpr int LDA = 264;   // 256 + 8 bf16 pad -> 528B row stride, bank-safe

__global__ __launch_bounds__(128)
void nope_gemm(const float* __restrict__ q_orig,  // [N,32,128]
               const float* __restrict__ k_orig,  // [N,8,128]
               const short* __restrict__ MnT,     // [64][1024] bf16
               float* __restrict__ out_iq,        // [N,4,128]
               float* __restrict__ out_ik)        // [N,128]
{
    __shared__ short sA[32 * LDA];
    const int tid  = threadIdx.x;
    const int lane = tid & 63, wave = tid >> 6;
    const int m    = lane & 15, quad = lane >> 4;
    const bool isQ = blockIdx.x < 1024;

    v4f acc[4];
#pragma unroll
    for (int t = 0; t < 4; ++t) acc[t] = (v4f){0.f, 0.f, 0.f, 0.f};

    for (int c = 0; c < 4; ++c) {
        if (isQ) {
            const float* src = q_orig + (size_t)blockIdx.x * 32768 + c * 1024;
#pragma unroll
            for (int i = 0; i < 16; ++i) {
                const int e  = (i * 128 + tid) * 4;   // float idx in 8192-chunk
                const int np = e >> 10, r8 = e & 1023;
                const float4 f = *(const float4*)(src + np * 4096 + r8);
                const int hl = r8 >> 7, dp = r8 & 127;
                const int row = np * 4 + (hl & 3);
                const int lk  = (hl >> 2) * 128 + dp;
                short4 b4 = { f2bf(f.x), f2bf(f.y), f2bf(f.z), f2bf(f.w) };
                *(short4*)&sA[row * LDA + lk] = b4;
            }
        } else {
            const float* src = k_orig + (size_t)(blockIdx.x - 1024) * 32768 + c * 256;
#pragma unroll
            for (int i = 0; i < 16; ++i) {
                const int e  = (i * 128 + tid) * 4;
                const int np = e >> 8, lk = e & 255;
                const float4 f = *(const float4*)(src + np * 1024 + lk);
                short4 b4 = { f2bf(f.x), f2bf(f.y), f2bf(f.z), f2bf(f.w) };
                *(short4*)&sA[np * LDA + lk] = b4;
            }
        }
        __syncthreads();
        const short* arow = sA + (wave * 16 + m) * LDA;
#pragma unroll
        for (int ks = 0; ks < 8; ++ks) {
            const v8s a = *(const v8s*)(arow + ks * 32 + quad * 8);
            const int kglob = c * 256 + ks * 32 + quad * 8;
#pragma unroll
            for (int ct = 0; ct < 4; ++ct) {
                const v8s b = *(const v8s*)(MnT + (ct * 16 + m) * 1024 + kglob);
                acc[ct] = __builtin_amdgcn_mfma_f32_16x16x32_bf16(a, b, acc[ct], 0, 0, 0);
            }
        }
        __syncthreads();
    }

    // C/D layout: col=lane&15, row_in_tile=quad*4+i
#pragma unroll
    for (int ct = 0; ct < 4; ++ct) {
        const int col = 64 + ct * 16 + m;
#pragma unroll
        for (int i = 0; i < 4; ++i) {
            const int row = wave * 16 + quad * 4 + i;
            if (isQ) {
                const int tok = blockIdx.x * 8 + (row >> 2);
                out_iq[(size_t)tok * 512 + (row & 3) * 128 + col] = acc[ct][i];
            } else {
                const int tok = (blockIdx.x - 1024) * 32 + row;
                out_ik[(size_t)tok * 128 + col] = acc[ct][i];
            }
        }
    }
}

// ---------------------------------------------------------------------------
// Rope half: out[:, 0:64]. M is sparse: 16 nonzeros per column.
// out[row][col] = sum_{g,b} src[g-head][dp(col,b)] * widx[B][g+8b][0]
//   B=col&31, part=col>>5, dp = part*64 + 4*(B&15) + (B>>4) + 2b
// Blocks 0..8191: Q token per block, wave = jj. Blocks 8192..10239: 4 k-rows.
// ---------------------------------------------------------------------------
__global__ __launch_bounds__(256)
void rope_kernel(const float* __restrict__ q,     // [N,32,128]
                 const float* __restrict__ k,     // [N,8,128]
                 const float* __restrict__ widx,  // [32][16][16]
                 float* __restrict__ out_iq,
                 float* __restrict__ out_ik)
{
    const int lane = threadIdx.x & 63, wave = threadIdx.x >> 6;
    const int col = lane, B = col & 31, part = col >> 5;

    float wgt[16];
#pragma unroll
    for (int b = 0; b < 2; ++b)
#pragma unroll
        for (int g = 0; g < 8; ++g)
            wgt[b * 8 + g] = widx[B * 256 + (g + 8 * b) * 16];

    const int dp0 = part * 64 + 4 * (B & 15) + (B >> 4);
    float acc = 0.f;
    if (blockIdx.x < 8192) {
        const float* src = q + (size_t)blockIdx.x * 4096 + wave * 128;
#pragma unroll
        for (int b = 0; b < 2; ++b)
#pragma unroll
            for (int g = 0; g < 8; ++g)
                acc += src[g * 512 + dp0 + 2 * b] * wgt[b * 8 + g];
        out_iq[(size_t)blockIdx.x * 512 + wave * 128 + col] = acc;
    } else {
        const int n = (blockIdx.x - 8192) * 4 + wave;
        const float* src = k + (size_t)n * 1024;
#pragma unroll
        for (int b = 0; b < 2; ++b)
#pragma unroll
            for (int g = 0; g < 8; ++g)
                acc += src[g * 128 + dp0 + 2 * b] * wgt[b * 8 + g];
        out_ik[(size_t)n * 128 + col] = acc;
    }
}

// ---------------------------------------------------------------------------
// Weights: one token per wave. Lane handles tasks t=lane and t=lane+64
// (t = h*4+rr). Coalesced W2 loads; butterfly reduce over bits {0,1,4,5}.
// ---------------------------------------------------------------------------
__global__ __launch_bounds__(256)
void weights_kernel(const float* __restrict__ v,   // [N,8,128]
                    const float* __restrict__ W2,  // [2][32][64][4]
                    float* __restrict__ out_w)     // [N,4]
{
    const int lane = threadIdx.x & 63, wave = threadIdx.x >> 6;
    const int n = blockIdx.x * 4 + wave;
    const int g1 = lane >> 4;   // task1 g; task2 g = g1+4
    const float4* v1 = (const float4*)(v + (size_t)n * 1024 + g1 * 128);
    const float4* v2 = (const float4*)(v + (size_t)n * 1024 + (g1 + 4) * 128);
    const float4* w1 = (const float4*)(W2) + lane;
    const float4* w2 = (const float4*)(W2 + 8192) + lane;
    float a1 = 0.f, a2 = 0.f;
#pragma unroll 8
    for (int i = 0; i < 32; ++i) {
        const float4 x1 = v1[i], x2 = v2[i];
        const float4 y1 = w1[i * 64], y2 = w2[i * 64];
        a1 += x1.x * y1.x + x1.y * y1.y + x1.z * y1.z + x1.w * y1.w;
        a2 += x2.x * y2.x + x2.y * y2.y + x2.z * y2.z + x2.w * y2.w;
    }
    float s = a1 * a1 + a2 * a2;
    s += __shfl_xor(s, 1);
    s += __shfl_xor(s, 2);
    s += __shfl_xor(s, 16);
    s += __shfl_xor(s, 32);
    if ((lane & 51) == 0)                       // lanes 0,4,8,12
        out_w[(size_t)n * 4 + (lane >> 2)] = sqrtf(s);
}

extern "C" void kernel_launch(void* const* d_in, const int* in_sizes, int n_in,
                              void* d_out, int out_size, void* d_ws, size_t ws_size,
                              hipStream_t stream) {
    const float* q      = (const float*)d_in[0];
    const float* k      = (const float*)d_in[1];
    const float* v      = (const float*)d_in[2];
    const float* q_orig = (const float*)d_in[3];
    const float* k_orig = (const float*)d_in[4];
    const float* widx   = (const float*)d_in[5];
    const float* wn     = (const float*)d_in[6];
    const float* vt     = (const float*)d_in[7];

    float* out_iq = (float*)d_out;
    float* out_ik = out_iq + (size_t)8192 * 512;   // +4,194,304
    float* out_w  = out_ik + (size_t)8192 * 128;   // +1,048,576

    short* MnT = (short*)d_ws;                     // 128 KB
    float* W2  = (float*)((char*)d_ws + 131072);   // 64 KB

    hipLaunchKernelGGL(build_tables, dim3(320), dim3(256), 0, stream,
                       widx, wn, vt, MnT, W2);
    hipLaunchKernelGGL(nope_gemm, dim3(1280), dim3(128), 0, stream,
                       q_orig, k_orig, MnT, out_iq, out_ik);
    hipLaunchKernelGGL(rope_kernel, dim3(10240), dim3(256), 0, stream,
                       q, k, widx, out_iq, out_ik);
    hipLaunchKernelGGL(weights_kernel, dim3(2048), dim3(256), 0, stream,
                       v, W2, out_w);
}

// Round 4
// 485.471 us; speedup vs baseline: 1.0178x; 1.0178x over previous
//
#include <hip/hip_runtime.h>
#include <math.h>

typedef short v8s __attribute__((ext_vector_type(8)));
typedef float v4f __attribute__((ext_vector_type(4)));

__device__ __forceinline__ short f2bf(float f) {
    union { float f; unsigned u; } x; x.f = f;
    unsigned r = x.u + 0x7FFFu + ((x.u >> 16) & 1u);
    return (short)(r >> 16);
}

// ---------------------------------------------------------------------------
// Build tables:
//  MT [128 cols][1024 k] bf16 : full projection matrix (rope cols sparse).
//    k = g*128+dp ; part=dp>>6, dpp=dp&63, B=(dpp&1)*16+(dpp>>2), c=g+8*((dpp>>1)&1)
//    col<64  : (col == part*32+B) ? widx[B][c][0] : 0
//    col>=64 : sum_{o=1..15} widx[B][c][o] * wn[col-64][part*480+B*15+o-1]
//  W2 [2][32][64][4] f32 : vt rearranged for coalesced weights loads.
// ---------------------------------------------------------------------------
__global__ __launch_bounds__(256)
void build_tables(const float* __restrict__ widx,  // [32][16][16]
                  const float* __restrict__ wn,    // [64][960]
                  const float* __restrict__ vt,    // [32][128][4]
                  short* __restrict__ MT,
                  float* __restrict__ W2)
{
    const int idx = blockIdx.x * 256 + threadIdx.x;   // 147456 total
    if (idx < 131072) {
        const int col = idx >> 10, kk = idx & 1023;
        const int g = kk >> 7, dp = kk & 127;
        const int part = dp >> 6, dpp = dp & 63;
        const int B = (dpp & 1) * 16 + (dpp >> 2);
        const int c = g + 8 * ((dpp >> 1) & 1);
        float val;
        if (col < 64) {
            val = (col == part * 32 + B) ? widx[B * 256 + c * 16] : 0.f;
        } else {
            const float* wrow = wn + (col - 64) * 960 + part * 480 + B * 15;
            const float* wi   = widx + B * 256 + c * 16;
            float s = 0.f;
#pragma unroll
            for (int o = 1; o < 16; ++o) s += wi[o] * wrow[o - 1];
            val = s;
        }
        MT[idx] = f2bf(val);
    } else {
        const int t = idx - 131072;                   // [0, 16384)
        const int cc = t & 3, l = (t >> 2) & 63, i = (t >> 8) & 31, s = t >> 13;
        const int h = (l >> 2) + 16 * s, rr = l & 3, d = i * 4 + cc;
        W2[t] = vt[h * 512 + d * 4 + rr];
    }
}

// ---------------------------------------------------------------------------
// Fused GEMM: Out[40960][128] = A[40960][1024] x M[1024][128]
//   cols 0..63  use A from q/k (rope), cols 64..127 from q_orig/k_orig (nope).
// Blocks 0..511:   Q — 16 tokens, 64 rows (row = tok*4+jj), A[r][g*128+dp] =
//                  q[n][g*4+jj][dp]. K-chunk 128 == one g: coalesced stream.
// Blocks 512..639: K — 64 tokens, 64 rows, A[r][k] = k[n][k] (contiguous).
// LDS: bf16 A tiles for both tensors, row stride 136 (272B, conflict-clean).
// ---------------------------------------------------------------------------
constexpr int LDA = 136;

__global__ __launch_bounds__(256, 4)
void fused_gemm(const float* __restrict__ q,       // [N,32,128]
                const float* __restrict__ k,       // [N,8,128]
                const float* __restrict__ q_orig,  // [N,32,128]
                const float* __restrict__ k_orig,  // [N,8,128]
                const short* __restrict__ MT,      // [128][1024] bf16
                float* __restrict__ out_iq,        // [N,4,128]
                float* __restrict__ out_ik)        // [N,128]
{
    __shared__ short sR[64 * LDA];
    __shared__ short sN[64 * LDA];
    const int tid  = threadIdx.x;
    const int lane = tid & 63, wave = tid >> 6;
    const int m    = lane & 15, quad = lane >> 4;
    const bool isQ = blockIdx.x < 512;

    v4f acc[8];
#pragma unroll
    for (int t = 0; t < 8; ++t) acc[t] = (v4f){0.f, 0.f, 0.f, 0.f};

    const float* srcR;
    const float* srcN;
    if (isQ) {
        srcR = q      + (size_t)blockIdx.x * 65536;   // 16 tokens * 4096
        srcN = q_orig + (size_t)blockIdx.x * 65536;
    } else {
        srcR = k      + (size_t)(blockIdx.x - 512) * 65536;  // 64 tokens * 1024
        srcN = k_orig + (size_t)(blockIdx.x - 512) * 65536;
    }

    for (int c = 0; c < 8; ++c) {
        // ---- stage: 64 rows x 128 k of both tensors, coalesced ----
        if (isQ) {
#pragma unroll
            for (int i = 0; i < 8; ++i) {
                const int e   = (i * 256 + tid) * 4;        // [0, 8192)
                const int tok = e >> 9, rem = e & 511;      // rem = jj*128+dp
                const int so  = tok * 4096 + c * 512 + rem;
                const float4 fr = *(const float4*)(srcR + so);
                const float4 fn = *(const float4*)(srcN + so);
                const int row = tok * 4 + (rem >> 7), dp = rem & 127;
                short4 br = { f2bf(fr.x), f2bf(fr.y), f2bf(fr.z), f2bf(fr.w) };
                short4 bn = { f2bf(fn.x), f2bf(fn.y), f2bf(fn.z), f2bf(fn.w) };
                *(short4*)&sR[row * LDA + dp] = br;
                *(short4*)&sN[row * LDA + dp] = bn;
            }
        } else {
#pragma unroll
            for (int i = 0; i < 8; ++i) {
                const int e   = (i * 256 + tid) * 4;
                const int tok = e >> 7, dp = e & 127;
                const int so  = tok * 1024 + c * 128 + dp;
                const float4 fr = *(const float4*)(srcR + so);
                const float4 fn = *(const float4*)(srcN + so);
                short4 br = { f2bf(fr.x), f2bf(fr.y), f2bf(fr.z), f2bf(fr.w) };
                short4 bn = { f2bf(fn.x), f2bf(fn.y), f2bf(fn.z), f2bf(fn.w) };
                *(short4*)&sR[tok * LDA + dp] = br;
                *(short4*)&sN[tok * LDA + dp] = bn;
            }
        }
        __syncthreads();

        const short* aR = sR + (wave * 16 + m) * LDA;
        const short* aN = sN + (wave * 16 + m) * LDA;
#pragma unroll
        for (int ks = 0; ks < 4; ++ks) {
            const v8s ar = *(const v8s*)(aR + ks * 32 + quad * 8);
            const v8s an = *(const v8s*)(aN + ks * 32 + quad * 8);
            const int kg = c * 128 + ks * 32 + quad * 8;
#pragma unroll
            for (int ct = 0; ct < 8; ++ct) {
                const v8s b = *(const v8s*)(MT + (ct * 16 + m) * 1024 + kg);
                acc[ct] = __builtin_amdgcn_mfma_f32_16x16x32_bf16(
                              (ct < 4) ? ar : an, b, acc[ct], 0, 0, 0);
            }
        }
        __syncthreads();
    }

    // C/D layout: col = lane&15 (+ct*16), row_in_tile = quad*4 + i
#pragma unroll
    for (int ct = 0; ct < 8; ++ct) {
        const int col = ct * 16 + m;
#pragma unroll
        for (int i = 0; i < 4; ++i) {
            const int row = wave * 16 + quad * 4 + i;
            if (isQ) {
                const int tok = blockIdx.x * 16 + (row >> 2);
                out_iq[(size_t)tok * 512 + (row & 3) * 128 + col] = acc[ct][i];
            } else {
                const int tok = (blockIdx.x - 512) * 64 + row;
                out_ik[(size_t)tok * 128 + col] = acc[ct][i];
            }
        }
    }
}

// ---------------------------------------------------------------------------
// Weights: one token per wave. Lane handles tasks t=lane and t=lane+64
// (t = h*4+rr). Coalesced W2 loads; butterfly reduce over bits {0,1,4,5}.
// ---------------------------------------------------------------------------
__global__ __launch_bounds__(256)
void weights_kernel(const float* __restrict__ v,   // [N,8,128]
                    const float* __restrict__ W2,  // [2][32][64][4]
                    float* __restrict__ out_w)     // [N,4]
{
    const int lane = threadIdx.x & 63, wave = threadIdx.x >> 6;
    const int n = blockIdx.x * 4 + wave;
    const int g1 = lane >> 4;
    const float4* v1 = (const float4*)(v + (size_t)n * 1024 + g1 * 128);
    const float4* v2 = (const float4*)(v + (size_t)n * 1024 + (g1 + 4) * 128);
    const float4* w1 = (const float4*)(W2) + lane;
    const float4* w2 = (const float4*)(W2 + 8192) + lane;
    float a1 = 0.f, a2 = 0.f;
#pragma unroll 8
    for (int i = 0; i < 32; ++i) {
        const float4 x1 = v1[i], x2 = v2[i];
        const float4 y1 = w1[i * 64], y2 = w2[i * 64];
        a1 += x1.x * y1.x + x1.y * y1.y + x1.z * y1.z + x1.w * y1.w;
        a2 += x2.x * y2.x + x2.y * y2.y + x2.z * y2.z + x2.w * y2.w;
    }
    float s = a1 * a1 + a2 * a2;
    s += __shfl_xor(s, 1);
    s += __shfl_xor(s, 2);
    s += __shfl_xor(s, 16);
    s += __shfl_xor(s, 32);
    if ((lane & 51) == 0)
        out_w[(size_t)n * 4 + (lane >> 2)] = sqrtf(s);
}

extern "C" void kernel_launch(void* const* d_in, const int* in_sizes, int n_in,
                              void* d_out, int out_size, void* d_ws, size_t ws_size,
                              hipStream_t stream) {
    const float* q      = (const float*)d_in[0];
    const float* k      = (const float*)d_in[1];
    const float* v      = (const float*)d_in[2];
    const float* q_orig = (const float*)d_in[3];
    const float* k_orig = (const float*)d_in[4];
    const float* widx   = (const float*)d_in[5];
    const float* wn     = (const float*)d_in[6];
    const float* vt     = (const float*)d_in[7];

    float* out_iq = (float*)d_out;
    float* out_ik = out_iq + (size_t)8192 * 512;
    float* out_w  = out_ik + (size_t)8192 * 128;

    short* MT = (short*)d_ws;                      // 256 KB
    float* W2 = (float*)((char*)d_ws + 262144);    // 64 KB

    hipLaunchKernelGGL(build_tables, dim3(576), dim3(256), 0, stream,
                       widx, wn, vt, MT, W2);
    hipLaunchKernelGGL(fused_gemm, dim3(640), dim3(256), 0, stream,
                       q, k, q_orig, k_orig, MT, out_iq, out_ik);
    hipLaunchKernelGGL(weights_kernel, dim3(2048), dim3(256), 0, stream,
                       v, W2, out_w);
}